// Round 1
// baseline (382.261 us; speedup 1.0000x reference)
//
#include <hip/hip_runtime.h>
#include <cstdint>
#include <math.h>

#define B_ROWS 4096
#define NT_COLS 8192
#define P_POS 8
#define K_NEG 1016
#define N_PAD 3079.0f          // B - (1+K)
#define A_C 1.57694f
#define BB_C 0.89506f
#define TEMP_C 0.15f

// ---- Threefry-2x32, 20 rounds, exactly JAX's schedule ----
__host__ __device__ __forceinline__ void tf2x32(uint32_t k0, uint32_t k1,
                                                uint32_t& x0, uint32_t& x1) {
  const uint32_t ks2 = k0 ^ k1 ^ 0x1BD11BDAu;
  x0 += k0; x1 += k1;
#define TF_RND(r) { x0 += x1; x1 = (x1 << (r)) | (x1 >> (32 - (r))); x1 ^= x0; }
  TF_RND(13) TF_RND(15) TF_RND(26) TF_RND(6)
  x0 += k1;  x1 += ks2 + 1u;
  TF_RND(17) TF_RND(29) TF_RND(16) TF_RND(24)
  x0 += ks2; x1 += k0 + 2u;
  TF_RND(13) TF_RND(15) TF_RND(26) TF_RND(6)
  x0 += k0;  x1 += k1 + 3u;
  TF_RND(17) TF_RND(29) TF_RND(16) TF_RND(24)
  x0 += k1;  x1 += ks2 + 4u;
  TF_RND(13) TF_RND(15) TF_RND(26) TF_RND(6)
  x0 += ks2; x1 += k0 + 5u;
#undef TF_RND
}

__device__ __forceinline__ float sim_fn(float x0, float x1, float xsq,
                                        float tx, float ty) {
  float tsq = tx * tx + ty * ty;
  float d2 = fmaxf(xsq + tsq - 2.0f * (x0 * tx + x1 * ty), 1e-12f);
  return 1.0f / (1.0f + A_C * powf(d2, BB_C));
}

__global__ __launch_bounds__(256) void cdr_row_kernel(
    const float* __restrict__ x_emb, const float* __restrict__ t_emb,
    const float* __restrict__ wf, const int* __restrict__ pos_idx,
    float* __restrict__ row_loss, float* __restrict__ out_atomic,
    uint32_t fk0, uint32_t fk1) {
  __shared__ uint32_t skey[NT_COLS];
  __shared__ uint32_t hist[256];
  __shared__ uint32_t sh_scal[3];   // 0: prefix, 1: remaining, 2: tie counter
  __shared__ int sh_pos[P_POS];
  __shared__ float sh_part[4];

  const int row = blockIdx.x;
  const int tid = threadIdx.x;

  if (tid < P_POS) sh_pos[tid] = pos_idx[row * P_POS + tid];
  if (tid == 0) sh_scal[2] = 0u;
  __syncthreads();

  const float x0 = x_emb[row * 2 + 0];
  const float x1 = x_emb[row * 2 + 1];
  const float xsq = x0 * x0 + x1 * x1;

  // ---- phase 1: scores -> order-preserving keys in LDS ----
  const uint32_t H = 16777216u;   // half of B*NT
  const bool lo_half = (row < 2048);
  for (int i = 0; i < NT_COLS / 256; ++i) {
    const int col = i * 256 + tid;
    const uint32_t n = (uint32_t)(row * NT_COLS + col);
    uint32_t a = lo_half ? n : (n - H);
    uint32_t b = lo_half ? (n + H) : n;
    tf2x32(fk0, fk1, a, b);
    const uint32_t bits = lo_half ? a : b;
    float f = __uint_as_float((bits >> 9) | 0x3f800000u) - 1.0f;
    float u = fmaxf(f + 1e-20f, 1e-20f);
    float g = -logf(-logf(u));
    float score = 0.75f * logf(wf[col]) + g;
    bool masked = false;
#pragma unroll
    for (int p = 0; p < P_POS; ++p) masked |= (col == sh_pos[p]);
    if (masked) score = -INFINITY;
    uint32_t sb = __float_as_uint(score);
    skey[col] = (sb & 0x80000000u) ? ~sb : (sb | 0x80000000u);
  }
  __syncthreads();

  // ---- phase 2: radix-select the K-th largest key ----
  uint32_t prefix = 0u, pmask = 0u, remaining = K_NEG;
  for (int shift = 24; shift >= 0; shift -= 8) {
    hist[tid] = 0u;
    __syncthreads();
    for (int i = 0; i < NT_COLS / 256; ++i) {
      const uint32_t key = skey[i * 256 + tid];
      if ((key & pmask) == prefix) atomicAdd(&hist[(key >> shift) & 0xFFu], 1u);
    }
    __syncthreads();
    if (tid == 0) {
      uint32_t cum = 0; int b;
      for (b = 255; b >= 0; --b) { cum += hist[b]; if (cum >= remaining) break; }
      uint32_t cnt_gt = cum - hist[b];
      sh_scal[0] = prefix | ((uint32_t)b << shift);
      sh_scal[1] = remaining - cnt_gt;
    }
    __syncthreads();
    prefix = sh_scal[0];
    remaining = sh_scal[1];
    pmask |= (0xFFu << shift);
  }
  const uint32_t theta = prefix;
  const uint32_t need_ties = remaining;

  // ---- phase 3: sum exp(sim/T) over selected negatives ----
  float sumexp = 0.0f;
  for (int i = 0; i < NT_COLS / 256; ++i) {
    const int col = i * 256 + tid;
    const uint32_t key = skey[col];
    bool inc = key > theta;
    if (key == theta) {
      uint32_t o = atomicAdd(&sh_scal[2], 1u);
      inc = (o < need_ties);
    }
    if (inc) {
      float tx = t_emb[col * 2 + 0];
      float ty = t_emb[col * 2 + 1];
      float s = sim_fn(x0, x1, xsq, tx, ty);
      sumexp += expf(s / TEMP_C);
    }
  }
  // block reduce (4 waves of 64)
  float v = sumexp;
#pragma unroll
  for (int off = 32; off > 0; off >>= 1) v += __shfl_down(v, off);
  if ((tid & 63) == 0) sh_part[tid >> 6] = v;
  __syncthreads();

  if (tid == 0) {
    float s = sh_part[0] + sh_part[1] + sh_part[2] + sh_part[3];
    float psum = 0.0f;
    for (int p = 0; p < P_POS; ++p) {
      int c = sh_pos[p];
      psum += sim_fn(x0, x1, xsq, t_emb[c * 2 + 0], t_emb[c * 2 + 1]);
    }
    float pos = psum * (1.0f / P_POS);
    float zpos = pos / TEMP_C;
    float S = s + expf(zpos) + N_PAD;
    float loss = logf(S) - zpos;
    if (row_loss) row_loss[row] = loss;
    else atomicAdd(out_atomic, loss * (1.0f / B_ROWS));
  }
}

__global__ __launch_bounds__(256) void cdr_reduce_kernel(
    const float* __restrict__ row_loss, float* __restrict__ out) {
  __shared__ float part[4];
  float s = 0.0f;
  for (int i = threadIdx.x; i < B_ROWS; i += 256) s += row_loss[i];
#pragma unroll
  for (int off = 32; off > 0; off >>= 1) s += __shfl_down(s, off);
  if ((threadIdx.x & 63) == 0) part[threadIdx.x >> 6] = s;
  __syncthreads();
  if (threadIdx.x == 0)
    out[0] = (part[0] + part[1] + part[2] + part[3]) * (1.0f / B_ROWS);
}

__global__ void cdr_zero_kernel(float* __restrict__ out) { out[0] = 0.0f; }

extern "C" void kernel_launch(void* const* d_in, const int* in_sizes, int n_in,
                              void* d_out, int out_size, void* d_ws, size_t ws_size,
                              hipStream_t stream) {
  const float* x_emb = (const float*)d_in[0];
  const float* t_emb = (const float*)d_in[1];
  const float* wf    = (const float*)d_in[2];
  const int*   pidx  = (const int*)d_in[3];
  float* out = (float*)d_out;

  // folded key: fold_in(key(0), 1) = threefry2x32((0,0), (0,1))
  uint32_t fk0 = 0u, fk1 = 1u;
  tf2x32(0u, 0u, fk0, fk1);

  const bool use_ws = (ws_size >= (size_t)B_ROWS * sizeof(float));
  float* row_loss = use_ws ? (float*)d_ws : nullptr;

  if (!use_ws) {
    hipLaunchKernelGGL(cdr_zero_kernel, dim3(1), dim3(1), 0, stream, out);
  }
  hipLaunchKernelGGL(cdr_row_kernel, dim3(B_ROWS), dim3(256), 0, stream,
                     x_emb, t_emb, wf, pidx, row_loss, out, fk0, fk1);
  if (use_ws) {
    hipLaunchKernelGGL(cdr_reduce_kernel, dim3(1), dim3(256), 0, stream,
                       row_loss, out);
  }
}

// Round 3
// 157.789 us; speedup vs baseline: 2.4226x; 2.4226x over previous
//
#include <hip/hip_runtime.h>
#include <cstdint>
#include <math.h>

#define B_ROWS 4096
#define NT_COLS 8192
#define P_POS 8
#define K_NEG 1016
#define N_PAD 3079.0f          // B - (1+K)
#define A_C 1.57694f
#define BB_C 0.89506f
#define INV_T 6.66666666667f
#define THREADS 512
#define EPT (NT_COLS / THREADS)   // 16
#define LN2_F 0.69314718056f
#define INV_LN2_F 1.44269504089f

// hw transcendental wrappers (avoid glibc name collisions)
__device__ __forceinline__ float hw_log2(float x) { return __builtin_amdgcn_logf(x); }
__device__ __forceinline__ float hw_exp2(float x) { return __builtin_amdgcn_exp2f(x); }
__device__ __forceinline__ float hw_ln(float x) { return hw_log2(x) * LN2_F; }

// ---- Threefry-2x32, 20 rounds, exactly JAX's schedule ----
__host__ __device__ __forceinline__ void tf2x32(uint32_t k0, uint32_t k1,
                                                uint32_t& x0, uint32_t& x1) {
  const uint32_t ks2 = k0 ^ k1 ^ 0x1BD11BDAu;
  x0 += k0; x1 += k1;
#define TF_RND(r) { x0 += x1; x1 = (x1 << (r)) | (x1 >> (32 - (r))); x1 ^= x0; }
  TF_RND(13) TF_RND(15) TF_RND(26) TF_RND(6)
  x0 += k1;  x1 += ks2 + 1u;
  TF_RND(17) TF_RND(29) TF_RND(16) TF_RND(24)
  x0 += ks2; x1 += k0 + 2u;
  TF_RND(13) TF_RND(15) TF_RND(26) TF_RND(6)
  x0 += k0;  x1 += k1 + 3u;
  TF_RND(17) TF_RND(29) TF_RND(16) TF_RND(24)
  x0 += k1;  x1 += ks2 + 4u;
  TF_RND(13) TF_RND(15) TF_RND(26) TF_RND(6)
  x0 += ks2; x1 += k0 + 5u;
#undef TF_RND
}

// fast sim: 1/(1 + A * d2^BB) with hw log2/exp2
__device__ __forceinline__ float sim_fast(float x0, float x1, float xsq,
                                          float tx, float ty) {
  float tsq = tx * tx + ty * ty;
  float d2 = fmaxf(xsq + tsq - 2.0f * (x0 * tx + x1 * ty), 1e-12f);
  return 1.0f / (1.0f + A_C * hw_exp2(BB_C * hw_log2(d2)));
}

__global__ void prelog_kernel(const float* __restrict__ wf,
                              float* __restrict__ logw) {
  int i = blockIdx.x * 256 + threadIdx.x;
  if (i < NT_COLS) logw[i] = 0.75f * logf(wf[i]);
}

__global__ __launch_bounds__(THREADS, 8) void cdr_row_kernel(
    const float* __restrict__ x_emb, const float* __restrict__ t_emb,
    const float* __restrict__ logw, const float* __restrict__ wf,
    const int* __restrict__ pos_idx,
    float* __restrict__ row_loss, float* __restrict__ out_atomic,
    uint32_t fk0, uint32_t fk1) {
  __shared__ uint32_t skey[NT_COLS];      // 32 KB
  __shared__ uint32_t hist[4][256];       // 4 KB, one copy per 2 waves
  __shared__ uint32_t ssum[256];
  __shared__ uint32_t sh_scal[4];         // 0: prefix, 1: remaining, 2: tie ctr
  __shared__ int sh_pos[P_POS];
  __shared__ float sh_part[8];

  const int row = blockIdx.x;
  const int tid = threadIdx.x;

  if (tid < P_POS) sh_pos[tid] = pos_idx[row * P_POS + tid];
  if (tid == 0) sh_scal[2] = 0u;
  __syncthreads();

  const float x0 = x_emb[row * 2 + 0];
  const float x1 = x_emb[row * 2 + 1];
  const float xsq = x0 * x0 + x1 * x1;

  // ---- phase 1: threefry -> gumbel -> score keys in LDS ----
  const uint32_t H = 16777216u;   // (B*NT)/2
  const bool lo = (row < 2048);
#pragma unroll 1
  for (int i = 0; i < EPT; ++i) {
    const int col = i * THREADS + tid;
    const uint32_t n = (uint32_t)(row * NT_COLS + col);
    uint32_t a = lo ? n : (n - H);
    uint32_t b = lo ? (n + H) : n;
    tf2x32(fk0, fk1, a, b);
    const uint32_t bits = lo ? a : b;
    float f = __uint_as_float((bits >> 9) | 0x3f800000u) - 1.0f;
    float u = fmaxf(f, 1e-20f);                 // f + 1e-20 == f unless f==0
    float g = -hw_ln(-hw_ln(u));                // hw log, ~1e-7 rel err
    float lw = logw ? logw[col] : 0.75f * hw_ln(wf[col]);
    float score = lw + g;
    bool masked = false;
#pragma unroll
    for (int p = 0; p < P_POS; ++p) masked |= (col == sh_pos[p]);
    uint32_t sb = __float_as_uint(score);
    uint32_t key = sb ^ (0x80000000u | (uint32_t)(-(int32_t)(sb >> 31)));
    skey[col] = masked ? 0u : key;              // 0 == below every real score
  }
  __syncthreads();

  // ---- phase 2: radix-select the K-th largest key (4 x 8-bit passes) ----
  uint32_t prefix = 0u, pmask = 0u, remaining = K_NEG;
  for (int shift = 24; shift >= 0; shift -= 8) {
    ((uint32_t*)hist)[tid] = 0u;
    ((uint32_t*)hist)[tid + 512] = 0u;
    __syncthreads();
    uint32_t* myh = hist[tid >> 7];
#pragma unroll 1
    for (int i = 0; i < EPT; ++i) {
      const uint32_t key = skey[i * THREADS + tid];
      if ((key & pmask) == prefix) atomicAdd(&myh[(key >> shift) & 0xFFu], 1u);
    }
    __syncthreads();
    if (tid < 256) ssum[tid] = hist[0][tid] + hist[1][tid] + hist[2][tid] + hist[3][tid];
    __syncthreads();
    // parallel suffix scan: ssum[b] = sum_{j>=b} count[j]
    for (int off = 1; off < 256; off <<= 1) {
      uint32_t v = 0;
      if (tid < 256) { v = ssum[tid]; if (tid + off < 256) v += ssum[tid + off]; }
      __syncthreads();
      if (tid < 256) ssum[tid] = v;
      __syncthreads();
    }
    if (tid < 256) {
      uint32_t ge = ssum[tid];
      uint32_t gt = (tid == 255) ? 0u : ssum[tid + 1];
      if (ge >= remaining && gt < remaining) {
        sh_scal[0] = prefix | ((uint32_t)tid << shift);
        sh_scal[1] = remaining - gt;
      }
    }
    __syncthreads();
    prefix = sh_scal[0];
    remaining = sh_scal[1];
    pmask |= (0xFFu << shift);
  }
  const uint32_t theta = prefix;
  const uint32_t need_ties = remaining;

  // ---- phase 3: sum exp(sim/T) over selected negatives ----
  float acc = 0.0f;
#pragma unroll 1
  for (int i = 0; i < EPT; ++i) {
    const int col = i * THREADS + tid;
    const uint32_t key = skey[col];
    bool inc = key > theta;
    if (key == theta) inc = (atomicAdd(&sh_scal[2], 1u) < need_ties);
    if (inc) {
      float tx = t_emb[col * 2 + 0];
      float ty = t_emb[col * 2 + 1];
      float s = sim_fast(x0, x1, xsq, tx, ty);
      acc += hw_exp2(s * (INV_T * INV_LN2_F));   // exp(s/0.15) via exp2
    }
  }
  // block reduce (8 waves of 64)
#pragma unroll
  for (int off = 32; off > 0; off >>= 1) acc += __shfl_down(acc, off);
  if ((tid & 63) == 0) sh_part[tid >> 6] = acc;
  __syncthreads();

  if (tid == 0) {
    float s = 0.0f;
#pragma unroll
    for (int w = 0; w < 8; ++w) s += sh_part[w];
    float psum = 0.0f;
    for (int p = 0; p < P_POS; ++p) {
      int c = sh_pos[p];
      psum += sim_fast(x0, x1, xsq, t_emb[c * 2 + 0], t_emb[c * 2 + 1]);
    }
    float pos = psum * (1.0f / P_POS);
    float zpos = pos * INV_T;
    float S = s + hw_exp2(zpos * INV_LN2_F) + N_PAD;
    float loss = logf(S) - zpos;
    if (row_loss) row_loss[row] = loss;
    else atomicAdd(out_atomic, loss * (1.0f / B_ROWS));
  }
}

__global__ __launch_bounds__(256) void cdr_reduce_kernel(
    const float* __restrict__ row_loss, float* __restrict__ out) {
  __shared__ float part[4];
  float s = 0.0f;
  for (int i = threadIdx.x; i < B_ROWS; i += 256) s += row_loss[i];
#pragma unroll
  for (int off = 32; off > 0; off >>= 1) s += __shfl_down(s, off);
  if ((threadIdx.x & 63) == 0) part[threadIdx.x >> 6] = s;
  __syncthreads();
  if (threadIdx.x == 0)
    out[0] = (part[0] + part[1] + part[2] + part[3]) * (1.0f / B_ROWS);
}

__global__ void cdr_zero_kernel(float* __restrict__ out) { out[0] = 0.0f; }

extern "C" void kernel_launch(void* const* d_in, const int* in_sizes, int n_in,
                              void* d_out, int out_size, void* d_ws, size_t ws_size,
                              hipStream_t stream) {
  const float* x_emb = (const float*)d_in[0];
  const float* t_emb = (const float*)d_in[1];
  const float* wf    = (const float*)d_in[2];
  const int*   pidx  = (const int*)d_in[3];
  float* out = (float*)d_out;

  // folded key: fold_in(key(0), 1) = threefry2x32((0,0), (0,1))
  uint32_t fk0 = 0u, fk1 = 1u;
  tf2x32(0u, 0u, fk0, fk1);

  const bool has_logw = (ws_size >= (size_t)(NT_COLS + B_ROWS) * sizeof(float));
  const bool has_rl   = (ws_size >= (size_t)B_ROWS * sizeof(float));

  float* logw = nullptr;
  float* row_loss = nullptr;
  if (has_logw) { logw = (float*)d_ws; row_loss = (float*)d_ws + NT_COLS; }
  else if (has_rl) { row_loss = (float*)d_ws; }

  if (has_logw) {
    hipLaunchKernelGGL(prelog_kernel, dim3(NT_COLS / 256), dim3(256), 0, stream,
                       wf, logw);
  }
  if (!row_loss) {
    hipLaunchKernelGGL(cdr_zero_kernel, dim3(1), dim3(1), 0, stream, out);
  }
  hipLaunchKernelGGL(cdr_row_kernel, dim3(B_ROWS), dim3(THREADS), 0, stream,
                     x_emb, t_emb, logw, wf, pidx, row_loss, out, fk0, fk1);
  if (row_loss) {
    hipLaunchKernelGGL(cdr_reduce_kernel, dim3(1), dim3(256), 0, stream,
                       row_loss, out);
  }
}